// Round 5
// baseline (388.302 us; speedup 1.0000x reference)
//
#include <hip/hip_runtime.h>

typedef _Float16 h16;
typedef __attribute__((ext_vector_type(8))) _Float16 half8;
typedef __attribute__((ext_vector_type(4))) _Float16 half4;
typedef __attribute__((ext_vector_type(4))) float f32x4;
typedef __attribute__((ext_vector_type(16))) float f32x16;

#define LDH 264   // h-buffer row stride in fp16 elems (256 + 8 pad)
#define LDE 72    // ep-buffer row stride (64 + 8 pad)

// weight fragment offsets in d_ws (fp16 elements)
constexpr size_t OFF_P0 = 0;        // [64 ][256]
constexpr size_t OFF_P1 = 16384;    // [256][256]
constexpr size_t OFF_P2 = 81920;
constexpr size_t OFF_P3 = 147456;
constexpr size_t OFF_P4 = 212992;
constexpr size_t OFF_P5 = 278528;   // [320][256], ROTATED: rows 0..255 = h-part, 256..319 = ep-part
constexpr size_t OFF_P6 = 360448;
constexpr size_t OFF_P7 = 425984;
constexpr size_t OFF_FEAT = 491520; // [256][256]
constexpr size_t OFF_VIEWS = 557056;// [288][128] (rows 0..255 = feature, 256..282 ev, 283..287 zero)

__device__ __forceinline__ f32x16 mfma32(half8 a, half8 b, f32x16 c) {
  return __builtin_amdgcn_mfma_f32_32x32x16_f16(a, b, c, 0, 0, 0);
}

__device__ __forceinline__ half8 ldfrag(const h16* __restrict__ base, int frag, int l) {
  return *(const half8*)(base + (size_t)frag * 512 + (size_t)l * 8);
}

// fp32 [K][N] row-major -> pre-swizzled fp16 fragments for 32x32x16.
// Fragment (kt,nt): lane l's 8 fp16 = B[kt*16+(l>>5)*8+j][nt*32+(l&31)].
// New padded row r maps through rotation: pr = (r + rot) % Kp, then pad logic:
// pr<p -> src pr ; p<=pr<p+npad -> 0 ; else src (pr-npad).
__global__ void convw_kernel(const float* __restrict__ src, h16* __restrict__ dst,
                             int Ksrc, int N, int Kp, int p, int npad, int rot) {
  int t = blockIdx.x * 256 + threadIdx.x;
  int nfrags = (Kp >> 4) * (N >> 5);
  int frag = t >> 6;
  if (frag >= nfrags) return;
  int l = t & 63;
  int ntiles = N >> 5;
  int kt = frag / ntiles;
  int nt = frag - kt * ntiles;
  int col = nt * 32 + (l & 31);
  int kbase = kt * 16 + (l >> 5) * 8;
  half8 v;
#pragma unroll
  for (int j = 0; j < 8; ++j) {
    int pr = kbase + j + rot;
    if (pr >= Kp) pr -= Kp;
    float x = 0.f;
    if (pr < p) {
      x = src[(size_t)pr * N + col];
    } else if (pr >= p + npad) {
      int r = pr - npad;
      if (r < Ksrc) x = src[(size_t)r * N + col];
    }
    v[j] = (h16)x;
  }
  *(half8*)(dst + (size_t)frag * 512 + (size_t)l * 8) = v;
}

struct Params {
  const float* pts;
  const float* views;
  const h16* wf;
  const float* pb[8];
  const float* views_b;
  const float* feat_b;
  const float* alpha_w;
  const float* alpha_b;
  const float* rgb_w;
  const float* rgb_b;
  float* out;
};

// Epilogue: bias + (relu) + pack fp16, write both 32-row tiles to Y.
// D^T map (verified R4): lane -> row mt*32+(l&31), cols w*32+g*8+(l>>5)*4 .. +4
template <bool RELU>
__device__ __forceinline__ void epi(const f32x16& a0, const f32x16& a1,
                                    const float* __restrict__ bias,
                                    h16* __restrict__ Y, int w, int l, int lr) {
#pragma unroll
  for (int mt = 0; mt < 2; ++mt) {
    const f32x16& A = mt ? a1 : a0;
    int row = mt * 32 + lr;
#pragma unroll
    for (int g = 0; g < 4; ++g) {
      int n0 = w * 32 + g * 8 + ((l >> 5) * 4);
      f32x4 bv = *(const f32x4*)(bias + n0);
      half4 pk;
#pragma unroll
      for (int i = 0; i < 4; ++i) {
        float v = A[g * 4 + i] + bv[i];
        if (RELU) v = fmaxf(v, 0.f);
        pk[i] = (h16)v;
      }
      *(half4*)(Y + (size_t)row * LDH + n0) = pk;
    }
  }
}

// One K>=256 layer. bf[0..7] hold this layer's frags 0..7 (prefetched by the
// previous layer). Head-loads frags 8..15 into bt. Phase B prefetches the NEXT
// layer's frags 0..7 into bf. EXTEP adds 4 kt from the ep buffer (K=320, L5).
template <bool RELU, bool EXTEP>
__device__ __forceinline__ void layer256(
    const h16* __restrict__ X, const h16* __restrict__ EPb, h16* __restrict__ Y,
    const h16* __restrict__ wcur, const h16* __restrict__ wnext,
    int nstride, int nbase, const float* __restrict__ bias,
    half8 (&bf)[8], half8 (&bt)[8], int w, int l, int lr, int lko) {
#pragma unroll
  for (int j = 0; j < 8; ++j) bt[j] = ldfrag(wcur, (8 + j) * 8 + w, l);
  half8 bep[4];
  f32x16 acc0 = (f32x16)0.f, acc1 = (f32x16)0.f;
  // phase A: rows 0..31
#pragma unroll
  for (int kt = 0; kt < 16; ++kt) {
    half8 a = *(const half8*)(X + (size_t)lr * LDH + kt * 16 + lko);
    half8 b = kt < 8 ? bf[kt] : bt[kt - 8];
    acc0 = mfma32(b, a, acc0);
    if (EXTEP && kt == 7) {
#pragma unroll
      for (int j = 0; j < 4; ++j) bep[j] = ldfrag(wcur, (16 + j) * 8 + w, l);
    }
  }
  if (EXTEP) {
#pragma unroll
    for (int j = 0; j < 4; ++j) {
      half8 a = *(const half8*)(EPb + (size_t)lr * LDE + j * 16 + lko);
      acc0 = mfma32(bep[j], a, acc0);
    }
  }
  // phase B: rows 32..63, prefetch next layer's frags 0..7
#pragma unroll
  for (int kt = 0; kt < 16; ++kt) {
    half8 a = *(const half8*)(X + (size_t)(32 + lr) * LDH + kt * 16 + lko);
    half8 b = kt < 8 ? bf[kt] : bt[kt - 8];
    acc1 = mfma32(b, a, acc1);
    if (kt < 8) bf[kt] = ldfrag(wnext, kt * nstride + nbase, l);
  }
  if (EXTEP) {
#pragma unroll
    for (int j = 0; j < 4; ++j) {
      half8 a = *(const half8*)(EPb + (size_t)(32 + lr) * LDE + j * 16 + lko);
      acc1 = mfma32(bep[j], a, acc1);
    }
  }
  epi<RELU>(acc0, acc1, bias, Y, w, l, lr);
  __syncthreads();
}

__global__ __launch_bounds__(512, 4) void nerf_kernel(Params P) {
  __shared__ __align__(16) h16 ep[64 * LDE];
  __shared__ __align__(16) h16 h0[64 * LDH];
  __shared__ __align__(16) h16 h1[64 * LDH];
  __shared__ __align__(16) h16 evp[32];

  const int tid = threadIdx.x;
  const int w = tid >> 6, l = tid & 63;
  const int lr = l & 31;
  const int lko = (l >> 5) * 8;
  const int ray = blockIdx.x;
  const h16* wf = P.wf;

  // issue L0's weight frags immediately (independent of LDS)
  half8 bt[8];
#pragma unroll
  for (int j = 0; j < 4; ++j) bt[j] = ldfrag(wf + OFF_P0, j * 8 + w, l);

  // ---- embeddings: all 512 threads; thread (s=tid>>3, q=tid&7) does 8 cols ----
  {
    const int s = tid >> 3, q = tid & 7;
    const float* ps = P.pts + ((size_t)ray * 64 + s) * 3;
    const float x0 = ps[0], x1 = ps[1], x2 = ps[2];
    half8 v;
#pragma unroll
    for (int j = 0; j < 8; ++j) {
      int p = q * 8 + j;
      float val;
      if (p < 3) {
        val = p == 0 ? x0 : (p == 1 ? x1 : x2);
      } else if (p < 63) {
        int t = p - 3;
        int f = t / 6, rem = t % 6, d = rem % 3;
        float x = (d == 0 ? x0 : (d == 1 ? x1 : x2)) * (float)(1 << f);
        val = (rem < 3) ? sinf(x) : cosf(x);
      } else {
        val = 0.f;
      }
      v[j] = (h16)val;
    }
    *(half8*)(ep + (size_t)s * LDE + q * 8) = v;
  }
  if (tid < 32) {
    const int idx = tid;
    float v = 0.f;
    if (idx < 27) {
      if (idx < 3) {
        v = P.views[(size_t)ray * 3 + idx];
      } else {
        const int f = (idx - 3) / 6, rem = (idx - 3) % 6, d = rem % 3;
        const float x = P.views[(size_t)ray * 3 + d] * (float)(1 << f);
        v = (rem < 3) ? sinf(x) : cosf(x);
      }
    }
    evp[idx] = (h16)v;
  }
  __syncthreads();

  half8 bf[8];

  // ---- L0: K=64 from ep ----
  {
    f32x16 acc0 = (f32x16)0.f, acc1 = (f32x16)0.f;
#pragma unroll
    for (int kt = 0; kt < 4; ++kt) {
      half8 a = *(const half8*)(ep + (size_t)lr * LDE + kt * 16 + lko);
      acc0 = mfma32(bt[kt], a, acc0);
    }
#pragma unroll
    for (int kt = 0; kt < 4; ++kt) {
      half8 a = *(const half8*)(ep + (size_t)(32 + lr) * LDE + kt * 16 + lko);
      acc1 = mfma32(bt[kt], a, acc1);
    }
#pragma unroll
    for (int j = 0; j < 8; ++j) bf[j] = ldfrag(wf + OFF_P1, j * 8 + w, l);
    epi<true>(acc0, acc1, P.pb[0], h0, w, l, lr);
    __syncthreads();
  }

  // ---- trunk L1..L7 (ping-pong h0/h1, one barrier per layer) ----
  layer256<true, false>(h0, ep, h1, wf + OFF_P1, wf + OFF_P2, 8, w, P.pb[1], bf, bt, w, l, lr, lko);
  layer256<true, false>(h1, ep, h0, wf + OFF_P2, wf + OFF_P3, 8, w, P.pb[2], bf, bt, w, l, lr, lko);
  layer256<true, false>(h0, ep, h1, wf + OFF_P3, wf + OFF_P4, 8, w, P.pb[3], bf, bt, w, l, lr, lko);
  layer256<true, false>(h1, ep, h0, wf + OFF_P4, wf + OFF_P5, 8, w, P.pb[4], bf, bt, w, l, lr, lko);
  // L5: K=320 (h-part kt 0..15 from h0, ep-part kt 16..19 from ep)
  layer256<true, true>(h0, ep, h1, wf + OFF_P5, wf + OFF_P6, 8, w, P.pb[5], bf, bt, w, l, lr, lko);
  layer256<true, false>(h1, ep, h0, wf + OFF_P6, wf + OFF_P7, 8, w, P.pb[6], bf, bt, w, l, lr, lko);
  layer256<true, false>(h0, ep, h1, wf + OFF_P7, wf + OFF_FEAT, 8, w, P.pb[7], bf, bt, w, l, lr, lko);

  // ---- alpha = h1 @ alpha_w + alpha_b (all 512 threads, vectorized) ----
  float alpha_reg;
  {
    const int s = tid >> 3, q = tid & 7;
    float sum = 0.f;
#pragma unroll
    for (int j = 0; j < 4; ++j) {
      half8 hv = *(const half8*)(h1 + (size_t)s * LDH + q * 32 + j * 8);
#pragma unroll
      for (int i = 0; i < 8; ++i)
        sum += (float)hv[i] * P.alpha_w[q * 32 + j * 8 + i];
    }
    sum += __shfl_xor(sum, 1);
    sum += __shfl_xor(sum, 2);
    sum += __shfl_xor(sum, 4);
    alpha_reg = sum + P.alpha_b[0];
  }

  // ---- feature = h1 @ feat_w + feat_b (no relu) -> h0; prefetch views frags ----
  layer256<false, false>(h1, ep, h0, wf + OFF_FEAT, wf + OFF_VIEWS, 4, (w >> 1),
                         P.feat_b, bf, bt, w, l, lr, lko);

  // ---- h2 = relu([feature, ev] @ views_w + views_b) -> h1[:, 0..127] ----
  // 8 waves x one 32x32 tile: row-tile r=w&1, col-tile c=w>>1. K=288.
  {
    const int r = w & 1, c = w >> 1;
    const h16* wV = wf + OFF_VIEWS;
#pragma unroll
    for (int j = 0; j < 8; ++j) bt[j] = ldfrag(wV, (8 + j) * 4 + c, l);
    half8 bev[2];
    f32x16 acc = (f32x16)0.f;
#pragma unroll
    for (int kt = 0; kt < 16; ++kt) {
      half8 a = *(const half8*)(h0 + (size_t)(r * 32 + lr) * LDH + kt * 16 + lko);
      half8 b = kt < 8 ? bf[kt] : bt[kt - 8];
      acc = mfma32(b, a, acc);
      if (kt == 7) {
        bev[0] = ldfrag(wV, 16 * 4 + c, l);
        bev[1] = ldfrag(wV, 17 * 4 + c, l);
      }
    }
#pragma unroll
    for (int j = 0; j < 2; ++j) {
      half8 a = *(const half8*)(evp + j * 16 + lko);  // broadcast (per-ray)
      acc = mfma32(bev[j], a, acc);
    }
    const int row = r * 32 + lr;
#pragma unroll
    for (int g = 0; g < 4; ++g) {
      int n0 = c * 32 + g * 8 + ((l >> 5) * 4);
      f32x4 bv = *(const f32x4*)(P.views_b + n0);
      half4 pk;
#pragma unroll
      for (int i = 0; i < 4; ++i)
        pk[i] = (h16)fmaxf(acc[g * 4 + i] + bv[i], 0.f);
      *(half4*)(h1 + (size_t)row * LDH + n0) = pk;
    }
    __syncthreads();
  }

  // ---- rgb + output (all 512 threads) ----
  {
    const int s = tid >> 3, q = tid & 7;
    float r0 = 0.f, r1 = 0.f, r2 = 0.f;
#pragma unroll
    for (int j = 0; j < 2; ++j) {
      half8 hv = *(const half8*)(h1 + (size_t)s * LDH + q * 16 + j * 8);
#pragma unroll
      for (int i = 0; i < 8; ++i) {
        const int kk = q * 16 + j * 8 + i;
        const float f = (float)hv[i];
        r0 += f * P.rgb_w[kk * 3 + 0];
        r1 += f * P.rgb_w[kk * 3 + 1];
        r2 += f * P.rgb_w[kk * 3 + 2];
      }
    }
    r0 += __shfl_xor(r0, 1); r0 += __shfl_xor(r0, 2); r0 += __shfl_xor(r0, 4);
    r1 += __shfl_xor(r1, 1); r1 += __shfl_xor(r1, 2); r1 += __shfl_xor(r1, 4);
    r2 += __shfl_xor(r2, 1); r2 += __shfl_xor(r2, 2); r2 += __shfl_xor(r2, 4);
    if (q == 0) {
      float4 o;
      o.x = r0 + P.rgb_b[0];
      o.y = r1 + P.rgb_b[1];
      o.z = r2 + P.rgb_b[2];
      o.w = alpha_reg;
      *(float4*)(P.out + ((size_t)ray * 64 + s) * 4) = o;
    }
  }
}

extern "C" void kernel_launch(void* const* d_in, const int* in_sizes, int n_in,
                              void* d_out, int out_size, void* d_ws, size_t ws_size,
                              hipStream_t stream) {
  h16* wsw = (h16*)d_ws;
  auto conv = [&](int idx, int Ksrc, int N, int Kp, int p, int npad, int rot, size_t off) {
    int nfrags = (Kp / 16) * (N / 32);
    int total = nfrags * 64;
    convw_kernel<<<(total + 255) / 256, 256, 0, stream>>>(
        (const float*)d_in[idx], wsw + off, Ksrc, N, Kp, p, npad, rot);
  };
  conv(2, 63, 256, 64, 63, 1, 0, OFF_P0);
  conv(4, 256, 256, 256, 256, 0, 0, OFF_P1);
  conv(6, 256, 256, 256, 256, 0, 0, OFF_P2);
  conv(8, 256, 256, 256, 256, 0, 0, OFF_P3);
  conv(10, 256, 256, 256, 256, 0, 0, OFF_P4);
  conv(12, 319, 256, 320, 63, 1, 64, OFF_P5);   // rotated: h-part first
  conv(14, 256, 256, 256, 256, 0, 0, OFF_P6);
  conv(16, 256, 256, 256, 256, 0, 0, OFF_P7);
  conv(20, 256, 256, 256, 256, 0, 0, OFF_FEAT);
  conv(18, 283, 128, 288, 283, 5, 0, OFF_VIEWS);

  Params P;
  P.pts = (const float*)d_in[0];
  P.views = (const float*)d_in[1];
  P.wf = wsw;
  for (int i = 0; i < 8; ++i) P.pb[i] = (const float*)d_in[3 + 2 * i];
  P.views_b = (const float*)d_in[19];
  P.feat_b = (const float*)d_in[21];
  P.alpha_w = (const float*)d_in[22];
  P.alpha_b = (const float*)d_in[23];
  P.rgb_w = (const float*)d_in[24];
  P.rgb_b = (const float*)d_in[25];
  P.out = (float*)d_out;

  nerf_kernel<<<4096, 512, 0, stream>>>(P);
}